// Round 4
// baseline (88.745 us; speedup 1.0000x reference)
//
#include <hip/hip_runtime.h>
#include <hip/hip_bf16.h>
#include <stdint.h>

#define BATCH 256
#define TSLOT 27
#define NTOT  (BATCH * TSLOT)   // 6912
#define DIM   1024
#define BM    128
#define BK2   32
#define NTILES 54               // NTOT / BM
#define NTRI  (NTILES * (NTILES + 1) / 2)  // 1485... grid uses 528 max active; use padded 528? grid = NTRI capped below
#define KST   (DIM / BK2)       // 32

typedef __attribute__((ext_vector_type(8))) short short8;
typedef __attribute__((ext_vector_type(4))) float f32x4;

// ---------- prep + scan: offsets, meta, clab tail, accum zero ----------
__global__ __launch_bounds__(256) void prepscan_kernel(const int* __restrict__ tgt,
                                                       int* __restrict__ offs,
                                                       int* __restrict__ meta,
                                                       int* __restrict__ clab,
                                                       float* __restrict__ accum) {
    int b = threadIdx.x;
    const int* t = tgt + b * TSLOT;
    int fz = 1;
    for (int i = 1; i < TSLOT; ++i) {
        if (t[i] == 0) { fz = i; break; }
    }
    __shared__ int sh[256];
    sh[b] = fz;
    __syncthreads();
    for (int d = 1; d < 256; d <<= 1) {
        int v = (b >= d) ? sh[b - d] : 0;
        __syncthreads();
        sh[b] += v;
        __syncthreads();
    }
    offs[b] = sh[b] - fz;  // exclusive
    if (b < 2) accum[b] = 0.0f;
    __syncthreads();
    int nv = sh[255];
    int npad = ((nv + 127) / 128) * 128;
    if (b == 255) {
        offs[256] = nv;
        meta[0] = nv;
        meta[1] = npad;
    }
    // clab tail: [nvalid, npad) = -1  (<= 127 entries)
    if (b < npad - nv) clab[nv + b] = -1;
}

// ---------- wave-per-row L2-normalize f32 -> bf16, scatter compacted ----------
__global__ __launch_bounds__(256) void norm_c_kernel(const float* __restrict__ in,
                                                     const int* __restrict__ tgt,
                                                     const int* __restrict__ offs,
                                                     __hip_bfloat16* __restrict__ cfb,
                                                     int* __restrict__ clab) {
    const int wv   = blockIdx.x * 4 + (threadIdx.x >> 6);  // source row
    const int lane = threadIdx.x & 63;
    const int b = wv / TSLOT, t = wv - b * TSLOT;
    const int o0 = offs[b], o1 = offs[b + 1];
    if (t >= o1 - o0) return;  // wave-uniform: invalid slot
    const int dest = o0 + t;
    const float* src = in + (size_t)wv * DIM + lane * 16;
    float4 v0 = *(const float4*)(src);
    float4 v1 = *(const float4*)(src + 4);
    float4 v2 = *(const float4*)(src + 8);
    float4 v3 = *(const float4*)(src + 12);
    float ss = v0.x*v0.x + v0.y*v0.y + v0.z*v0.z + v0.w*v0.w
             + v1.x*v1.x + v1.y*v1.y + v1.z*v1.z + v1.w*v1.w
             + v2.x*v2.x + v2.y*v2.y + v2.z*v2.z + v2.w*v2.w
             + v3.x*v3.x + v3.y*v3.y + v3.z*v3.z + v3.w*v3.w;
    #pragma unroll
    for (int off = 1; off < 64; off <<= 1) ss += __shfl_xor(ss, off);
    const float scale = 1.0f / fmaxf(sqrtf(ss), 1e-12f);
    unsigned short h[16];
    float f[16] = {v0.x,v0.y,v0.z,v0.w, v1.x,v1.y,v1.z,v1.w,
                   v2.x,v2.y,v2.z,v2.w, v3.x,v3.y,v3.z,v3.w};
    #pragma unroll
    for (int j = 0; j < 16; ++j) {
        __hip_bfloat16 hv = __float2bfloat16(f[j] * scale);
        h[j] = *(unsigned short*)&hv;
    }
    unsigned short* dst = (unsigned short*)cfb + (size_t)dest * DIM + lane * 16;
    *(ushort4*)(dst)      = *(ushort4*)&h[0];
    *(ushort4*)(dst + 4)  = *(ushort4*)&h[4];
    *(ushort4*)(dst + 8)  = *(ushort4*)&h[8];
    *(ushort4*)(dst + 12) = *(ushort4*)&h[12];
    if (lane == 0) clab[dest] = tgt[wv];
}

// ---------- symmetric fused GEMM: 4-deep counted-vmcnt pipeline, BK=32 ----------
__global__ __launch_bounds__(256) void gemm_kernel(const __hip_bfloat16* __restrict__ fb,
                                                   const int* __restrict__ clab,
                                                   const int* __restrict__ meta,
                                                   float* __restrict__ Ppos,
                                                   float* __restrict__ Pneg) {
    __shared__ __align__(16) char lds[65536];  // 4 bufs x (A 8KB + B 8KB)

    // XCD-chunked bijective swizzle over the 1485-triangle: chunk size 186? use 8*186>=1485
    // simpler: 1485 = 8*185 + 5 -> bijective split
    int orig = blockIdx.x;
    int xcd = orig & 7, sub = orig >> 3;        // sub < 186 for xcd<5 ... guard below
    // bijective: q=185, r=5 -> xcd<5 gets 186, else 185
    int t = (xcd < 5) ? (xcd * 186 + sub) : (5 * 186 + (xcd - 5) * 185 + sub);
    if (t >= NTRI) return;  // only when grid padding hits (grid = 1488)
    int bi = 0;
    while (t >= NTILES - bi) { t -= NTILES - bi; ++bi; }
    const int bj = bi + t;
    const int npad = meta[1];
    const int col0 = bj * BM;
    if (col0 >= npad) return;
    const int row0 = bi * BM;
    const bool diag = (bi == bj);

    const int tid  = threadIdx.x;
    const int lane = tid & 63;
    const int w    = tid >> 6;
    const int wm   = w >> 1, wn = w & 1;

    f32x4 acc[4][4] = {};
    const char* fbyte = (const char*)fb;

    // stage: 512 16B chunks per matrix; wave w covers chunks [w*128 + j*64 + lane]
    auto stage = [&](int s) {
        char* buf = lds + (s & 3) * 16384;
        const int k0b = s * 64;  // K byte offset
        #pragma unroll
        for (int j = 0; j < 2; ++j) {
            const int c = w * 128 + j * 64 + lane;
            const int r = c >> 2, ks = c & 3;
            const int srcoff = ((ks ^ ((r >> 1) & 3)) << 4);
            const char* ga = fbyte + (size_t)(row0 + r) * (DIM * 2) + k0b + srcoff;
            __builtin_amdgcn_global_load_lds(
                (const __attribute__((address_space(1))) void*)ga,
                (__attribute__((address_space(3))) void*)(buf + c * 16),
                16, 0, 0);
            const char* gb = fbyte + (size_t)(col0 + r) * (DIM * 2) + k0b + srcoff;
            __builtin_amdgcn_global_load_lds(
                (const __attribute__((address_space(1))) void*)gb,
                (__attribute__((address_space(3))) void*)(buf + 8192 + c * 16),
                16, 0, 0);
        }
    };

    const int rsel = lane & 15, tsl = lane >> 4;
    auto compute = [&](int s) {
        const char* bA = lds + (s & 3) * 16384;
        const char* bB = bA + 8192;
        short8 af[4], bf[4];
        #pragma unroll
        for (int m = 0; m < 4; ++m) {
            const int r = wm * 64 + m * 16 + rsel;
            af[m] = *(const short8*)(bA + r * 64 + ((tsl ^ ((r >> 1) & 3)) << 4));
        }
        #pragma unroll
        for (int n = 0; n < 4; ++n) {
            const int r = wn * 64 + n * 16 + rsel;
            bf[n] = *(const short8*)(bB + r * 64 + ((tsl ^ ((r >> 1) & 3)) << 4));
        }
        #pragma unroll
        for (int m = 0; m < 4; ++m)
            #pragma unroll
            for (int n = 0; n < 4; ++n)
                acc[m][n] = __builtin_amdgcn_mfma_f32_16x16x32_bf16(
                    af[m], bf[n], acc[m][n], 0, 0, 0);
    };

    stage(0); stage(1); stage(2);  // 12 loads outstanding
    #pragma unroll 1
    for (int s = 0; s < KST - 3; ++s) {
        asm volatile("s_waitcnt vmcnt(8)" ::: "memory");   // stage s landed (own wave)
        __builtin_amdgcn_s_barrier();                      // all waves' stage s landed
        asm volatile("" ::: "memory");
        stage(s + 3);                                      // overwrites buf (s-1): safe past barrier
        compute(s);
    }
    asm volatile("s_waitcnt vmcnt(8)" ::: "memory");
    __builtin_amdgcn_s_barrier();
    asm volatile("" ::: "memory");
    compute(KST - 3);
    asm volatile("s_waitcnt vmcnt(4)" ::: "memory");
    __builtin_amdgcn_s_barrier();
    asm volatile("" ::: "memory");
    compute(KST - 2);
    asm volatile("s_waitcnt vmcnt(0)" ::: "memory");
    __builtin_amdgcn_s_barrier();
    asm volatile("" ::: "memory");
    compute(KST - 1);

    // ---- epilogue: masked exp, wave-pair combine through LDS, coalesced stores ----
    const int c = rsel, g = tsl;
    float cpos[4] = {0, 0, 0, 0}, cneg[4] = {0, 0, 0, 0};
    float* fl = (float*)lds;  // bytes 0..4KB = buf0, last read at s=KST-4: safe

    #pragma unroll
    for (int m = 0; m < 4; ++m) {
        #pragma unroll
        for (int rg = 0; rg < 4; ++rg) {
            const int gi = row0 + wm * 64 + m * 16 + g * 4 + rg;
            const int li = clab[gi];
            float rp = 0.0f, rn = 0.0f;
            #pragma unroll
            for (int n = 0; n < 4; ++n) {
                const int gj = col0 + wn * 64 + n * 16 + c;
                const int lj = clab[gj];
                const float s = acc[m][n][rg];
                if (li >= 0 && lj >= 0) {
                    if (li == lj) { float e = __expf(-s); rp += e; cpos[n] += e; }
                    else          { float e = __expf(s);  rn += e; cneg[n] += e; }
                }
            }
            #pragma unroll
            for (int off = 1; off <= 8; off <<= 1) {
                rp += __shfl_xor(rp, off);
                rn += __shfl_xor(rn, off);
            }
            if (c == 0) {
                int lr = m * 16 + g * 4 + rg;
                fl[w * 64 + lr]       = rp;
                fl[256 + w * 64 + lr] = rn;
            }
        }
    }
    #pragma unroll
    for (int n = 0; n < 4; ++n) {
        float p = cpos[n], q = cneg[n];
        p += __shfl_xor(p, 16); p += __shfl_xor(p, 32);
        q += __shfl_xor(q, 16); q += __shfl_xor(q, 32);
        if (g == 0) {
            int lc = n * 16 + c;
            fl[512 + w * 64 + lc] = p;
            fl[768 + w * 64 + lc] = q;
        }
    }
    __syncthreads();
    if (tid < 128) {
        int sm = tid >> 6, lr = tid & 63;
        float rp = fl[(sm * 2 + 0) * 64 + lr] + fl[(sm * 2 + 1) * 64 + lr];
        float rn = fl[256 + (sm * 2 + 0) * 64 + lr] + fl[256 + (sm * 2 + 1) * 64 + lr];
        int gi = row0 + tid;
        Ppos[(size_t)bj * NTOT + gi] = rp;   // slot bj (>= bi), coalesced
        Pneg[(size_t)bj * NTOT + gi] = rn;
    } else if (!diag) {
        int j = tid - 128, sn = j >> 6, lc = j & 63;
        float p = fl[512 + sn * 64 + lc] + fl[512 + (2 + sn) * 64 + lc];
        float q = fl[768 + sn * 64 + lc] + fl[768 + (2 + sn) * 64 + lc];
        int gj = col0 + j;
        Ppos[(size_t)bi * NTOT + gj] = p;    // slot bi (< bj), coalesced
        Pneg[(size_t)bi * NTOT + gj] = q;
    }
}

// ---------- finalize: coalesced gather, masked mean of log1p(spos*sneg) ----------
__global__ __launch_bounds__(256) void finalize_kernel(const int* __restrict__ clab,
                                                       const int* __restrict__ meta,
                                                       const float* __restrict__ Ppos,
                                                       const float* __restrict__ Pneg,
                                                       float* __restrict__ accum) {
    int i = blockIdx.x * blockDim.x + threadIdx.x;
    const int npad = meta[1];
    const int nta = npad >> 7;
    float s = 0.0f, cnt = 0.0f;
    if (i < npad && clab[i] >= 0) {
        float sp = 0.0f, sn = 0.0f;
        for (int t = 0; t < nta; ++t) {
            sp += Ppos[(size_t)t * NTOT + i];
            sn += Pneg[(size_t)t * NTOT + i];
        }
        s = log1pf(sp * sn);
        cnt = 1.0f;
    }
    #pragma unroll
    for (int off = 1; off < 64; off <<= 1) {
        s   += __shfl_xor(s, off);
        cnt += __shfl_xor(cnt, off);
    }
    __shared__ float sh[8];
    int lane = threadIdx.x & 63, w = threadIdx.x >> 6;
    if (lane == 0) { sh[w] = s; sh[4 + w] = cnt; }
    __syncthreads();
    if (threadIdx.x == 0) {
        atomicAdd(&accum[0], sh[0] + sh[1] + sh[2] + sh[3]);
        atomicAdd(&accum[1], sh[4] + sh[5] + sh[6] + sh[7]);
    }
}

__global__ void writeout_kernel(const float* __restrict__ accum, float* __restrict__ out) {
    out[0] = accum[0] / accum[1];
}

extern "C" void kernel_launch(void* const* d_in, const int* in_sizes, int n_in,
                              void* d_out, int out_size, void* d_ws, size_t ws_size,
                              hipStream_t stream) {
    (void)in_sizes; (void)n_in; (void)out_size; (void)ws_size;
    const float* input_f = (const float*)d_in[0];
    const int*   target  = (const int*)d_in[1];
    float* out = (float*)d_out;

    char* ws = (char*)d_ws;
    const size_t FB_BYTES = (size_t)NTOT * DIM * 2;      // 14,155,776
    __hip_bfloat16* cfb = (__hip_bfloat16*)ws;
    char* p = ws + FB_BYTES;
    int*   clab  = (int*)p;            p += NTOT * 4;
    int*   offs  = (int*)p;            p += 4096;
    int*   meta  = (int*)p;            p += 256;
    float* accum = (float*)p;          p += 256;
    float* Ppos  = (float*)p;          p += (size_t)NTILES * NTOT * 4;  // 1.49 MB
    float* Pneg  = (float*)p;

    prepscan_kernel<<<dim3(1), dim3(256), 0, stream>>>(target, offs, meta, clab, accum);
    norm_c_kernel<<<dim3(NTOT / 4), dim3(256), 0, stream>>>(input_f, target, offs, cfb, clab);
    gemm_kernel<<<dim3(1488), dim3(256), 0, stream>>>(cfb, clab, meta, Ppos, Pneg);
    finalize_kernel<<<dim3((NTOT + 255) / 256), dim3(256), 0, stream>>>(clab, meta, Ppos, Pneg, accum);
    writeout_kernel<<<dim3(1), dim3(1), 0, stream>>>(accum, out);
}

// Round 5
// 83.927 us; speedup vs baseline: 1.0574x; 1.0574x over previous
//
#include <hip/hip_runtime.h>
#include <hip/hip_bf16.h>
#include <stdint.h>

#define BATCH 256
#define TSLOT 27
#define NTOT  (BATCH * TSLOT)   // 6912
#define DIM   1024
#define BM    128
#define BK2   32
#define NTILES 54               // NTOT / BM
#define NTRI  (NTILES * (NTILES + 1) / 2)  // 1485; active prefix ~ (npad/128) tiles
#define KST   (DIM / BK2)       // 32

typedef __attribute__((ext_vector_type(8))) short short8;
typedef __attribute__((ext_vector_type(4))) float f32x4;

// ---------- prep + scan: offsets, meta, clab tail, accum zero ----------
__global__ __launch_bounds__(256) void prepscan_kernel(const int* __restrict__ tgt,
                                                       int* __restrict__ offs,
                                                       int* __restrict__ meta,
                                                       int* __restrict__ clab,
                                                       float* __restrict__ accum) {
    int b = threadIdx.x;
    const int* t = tgt + b * TSLOT;
    int fz = 1;
    for (int i = 1; i < TSLOT; ++i) {
        if (t[i] == 0) { fz = i; break; }
    }
    __shared__ int sh[256];
    sh[b] = fz;
    __syncthreads();
    for (int d = 1; d < 256; d <<= 1) {
        int v = (b >= d) ? sh[b - d] : 0;
        __syncthreads();
        sh[b] += v;
        __syncthreads();
    }
    offs[b] = sh[b] - fz;  // exclusive
    if (b < 2) accum[b] = 0.0f;
    __syncthreads();
    int nv = sh[255];
    int npad = ((nv + 127) / 128) * 128;
    if (b == 255) {
        offs[256] = nv;
        meta[0] = nv;
        meta[1] = npad;
    }
    // clab tail: [nvalid, npad) = -1  (<= 127 entries)
    if (b < npad - nv) clab[nv + b] = -1;
}

// ---------- wave-per-row L2-normalize f32 -> bf16, scatter compacted ----------
__global__ __launch_bounds__(256) void norm_c_kernel(const float* __restrict__ in,
                                                     const int* __restrict__ tgt,
                                                     const int* __restrict__ offs,
                                                     __hip_bfloat16* __restrict__ cfb,
                                                     int* __restrict__ clab) {
    const int wv   = blockIdx.x * 4 + (threadIdx.x >> 6);  // source row
    const int lane = threadIdx.x & 63;
    const int b = wv / TSLOT, t = wv - b * TSLOT;
    const int o0 = offs[b], o1 = offs[b + 1];
    if (t >= o1 - o0) return;  // wave-uniform: invalid slot
    const int dest = o0 + t;
    const float* src = in + (size_t)wv * DIM + lane * 16;
    float4 v0 = *(const float4*)(src);
    float4 v1 = *(const float4*)(src + 4);
    float4 v2 = *(const float4*)(src + 8);
    float4 v3 = *(const float4*)(src + 12);
    float ss = v0.x*v0.x + v0.y*v0.y + v0.z*v0.z + v0.w*v0.w
             + v1.x*v1.x + v1.y*v1.y + v1.z*v1.z + v1.w*v1.w
             + v2.x*v2.x + v2.y*v2.y + v2.z*v2.z + v2.w*v2.w
             + v3.x*v3.x + v3.y*v3.y + v3.z*v3.z + v3.w*v3.w;
    #pragma unroll
    for (int off = 1; off < 64; off <<= 1) ss += __shfl_xor(ss, off);
    const float scale = 1.0f / fmaxf(sqrtf(ss), 1e-12f);
    unsigned short h[16];
    float f[16] = {v0.x,v0.y,v0.z,v0.w, v1.x,v1.y,v1.z,v1.w,
                   v2.x,v2.y,v2.z,v2.w, v3.x,v3.y,v3.z,v3.w};
    #pragma unroll
    for (int j = 0; j < 16; ++j) {
        __hip_bfloat16 hv = __float2bfloat16(f[j] * scale);
        h[j] = *(unsigned short*)&hv;
    }
    unsigned short* dst = (unsigned short*)cfb + (size_t)dest * DIM + lane * 16;
    *(ushort4*)(dst)      = *(ushort4*)&h[0];
    *(ushort4*)(dst + 4)  = *(ushort4*)&h[4];
    *(ushort4*)(dst + 8)  = *(ushort4*)&h[8];
    *(ushort4*)(dst + 12) = *(ushort4*)&h[12];
    if (lane == 0) clab[dest] = tgt[wv];
}

// ---------- symmetric fused GEMM: 4-deep counted-vmcnt pipeline, BK=32 ----------
// NOTE: no XCD swizzle. Active blocks are the data-dependent prefix of the
// triangle; consecutive blockIdx round-robins XCDs, spreading them evenly.
// (R4's chunked swizzle packed all active blocks onto 3/8 XCDs -> 65us.)
__global__ __launch_bounds__(256) void gemm_kernel(const __hip_bfloat16* __restrict__ fb,
                                                   const int* __restrict__ clab,
                                                   const int* __restrict__ meta,
                                                   float* __restrict__ Ppos,
                                                   float* __restrict__ Pneg) {
    __shared__ __align__(16) char lds[65536];  // 4 bufs x (A 8KB + B 8KB)

    int t = blockIdx.x;
    int bi = 0;
    while (t >= NTILES - bi) { t -= NTILES - bi; ++bi; }
    const int bj = bi + t;
    const int npad = meta[1];
    const int col0 = bj * BM;
    if (col0 >= npad) return;
    const int row0 = bi * BM;
    const bool diag = (bi == bj);

    const int tid  = threadIdx.x;
    const int lane = tid & 63;
    const int w    = tid >> 6;
    const int wm   = w >> 1, wn = w & 1;

    f32x4 acc[4][4] = {};
    const char* fbyte = (const char*)fb;

    // stage: 256 16B chunks per matrix per step; wave w covers chunks w*128+j*64+lane
    auto stage = [&](int s) {
        char* buf = lds + (s & 3) * 16384;
        const int k0b = s * 64;  // K byte offset
        #pragma unroll
        for (int j = 0; j < 2; ++j) {
            const int c = w * 128 + j * 64 + lane;
            const int r = c >> 2, ks = c & 3;
            const int srcoff = ((ks ^ ((r >> 1) & 3)) << 4);
            const char* ga = fbyte + (size_t)(row0 + r) * (DIM * 2) + k0b + srcoff;
            __builtin_amdgcn_global_load_lds(
                (const __attribute__((address_space(1))) void*)ga,
                (__attribute__((address_space(3))) void*)(buf + c * 16),
                16, 0, 0);
            const char* gb = fbyte + (size_t)(col0 + r) * (DIM * 2) + k0b + srcoff;
            __builtin_amdgcn_global_load_lds(
                (const __attribute__((address_space(1))) void*)gb,
                (__attribute__((address_space(3))) void*)(buf + 8192 + c * 16),
                16, 0, 0);
        }
    };

    const int rsel = lane & 15, tsl = lane >> 4;
    auto compute = [&](int s) {
        const char* bA = lds + (s & 3) * 16384;
        const char* bB = bA + 8192;
        short8 af[4], bf[4];
        #pragma unroll
        for (int m = 0; m < 4; ++m) {
            const int r = wm * 64 + m * 16 + rsel;
            af[m] = *(const short8*)(bA + r * 64 + ((tsl ^ ((r >> 1) & 3)) << 4));
        }
        #pragma unroll
        for (int n = 0; n < 4; ++n) {
            const int r = wn * 64 + n * 16 + rsel;
            bf[n] = *(const short8*)(bB + r * 64 + ((tsl ^ ((r >> 1) & 3)) << 4));
        }
        #pragma unroll
        for (int m = 0; m < 4; ++m)
            #pragma unroll
            for (int n = 0; n < 4; ++n)
                acc[m][n] = __builtin_amdgcn_mfma_f32_16x16x32_bf16(
                    af[m], bf[n], acc[m][n], 0, 0, 0);
    };

    stage(0); stage(1); stage(2);  // 12 loads/wave outstanding
    #pragma unroll 1
    for (int s = 0; s < KST - 3; ++s) {
        asm volatile("s_waitcnt vmcnt(8)" ::: "memory");   // stage s landed (own wave)
        __builtin_amdgcn_s_barrier();                      // all waves' stage s landed
        asm volatile("" ::: "memory");
        stage(s + 3);                                      // overwrites buf (s-1): all waves past compute(s-1)
        compute(s);
    }
    asm volatile("s_waitcnt vmcnt(8)" ::: "memory");
    __builtin_amdgcn_s_barrier();
    asm volatile("" ::: "memory");
    compute(KST - 3);
    asm volatile("s_waitcnt vmcnt(4)" ::: "memory");
    __builtin_amdgcn_s_barrier();
    asm volatile("" ::: "memory");
    compute(KST - 2);
    asm volatile("s_waitcnt vmcnt(0)" ::: "memory");
    __builtin_amdgcn_s_barrier();
    asm volatile("" ::: "memory");
    compute(KST - 1);

    // ---- epilogue: masked exp, wave-pair combine through LDS, coalesced stores ----
    // fl occupies buf0 (bytes 0..4K), last read by compute(28); compute(31) reads buf3 -> disjoint.
    const int c = rsel, g = tsl;
    float cpos[4] = {0, 0, 0, 0}, cneg[4] = {0, 0, 0, 0};
    float* fl = (float*)lds;

    #pragma unroll
    for (int m = 0; m < 4; ++m) {
        #pragma unroll
        for (int rg = 0; rg < 4; ++rg) {
            const int gi = row0 + wm * 64 + m * 16 + g * 4 + rg;
            const int li = clab[gi];
            float rp = 0.0f, rn = 0.0f;
            #pragma unroll
            for (int n = 0; n < 4; ++n) {
                const int gj = col0 + wn * 64 + n * 16 + c;
                const int lj = clab[gj];
                const float s = acc[m][n][rg];
                if (li >= 0 && lj >= 0) {
                    if (li == lj) { float e = __expf(-s); rp += e; cpos[n] += e; }
                    else          { float e = __expf(s);  rn += e; cneg[n] += e; }
                }
            }
            #pragma unroll
            for (int off = 1; off <= 8; off <<= 1) {
                rp += __shfl_xor(rp, off);
                rn += __shfl_xor(rn, off);
            }
            if (c == 0) {
                int lr = m * 16 + g * 4 + rg;
                fl[w * 64 + lr]       = rp;
                fl[256 + w * 64 + lr] = rn;
            }
        }
    }
    #pragma unroll
    for (int n = 0; n < 4; ++n) {
        float p = cpos[n], q = cneg[n];
        p += __shfl_xor(p, 16); p += __shfl_xor(p, 32);
        q += __shfl_xor(q, 16); q += __shfl_xor(q, 32);
        if (g == 0) {
            int lc = n * 16 + c;
            fl[512 + w * 64 + lc] = p;
            fl[768 + w * 64 + lc] = q;
        }
    }
    __syncthreads();
    if (tid < 128) {
        int sm = tid >> 6, lr = tid & 63;
        float rp = fl[(sm * 2 + 0) * 64 + lr] + fl[(sm * 2 + 1) * 64 + lr];
        float rn = fl[256 + (sm * 2 + 0) * 64 + lr] + fl[256 + (sm * 2 + 1) * 64 + lr];
        int gi = row0 + tid;
        Ppos[(size_t)bj * NTOT + gi] = rp;   // slot bj (>= bi), coalesced
        Pneg[(size_t)bj * NTOT + gi] = rn;
    } else if (!diag) {
        int j = tid - 128, sn = j >> 6, lc = j & 63;
        float p = fl[512 + sn * 64 + lc] + fl[512 + (2 + sn) * 64 + lc];
        float q = fl[768 + sn * 64 + lc] + fl[768 + (2 + sn) * 64 + lc];
        int gj = col0 + j;
        Ppos[(size_t)bi * NTOT + gj] = p;    // slot bi (< bj), coalesced
        Pneg[(size_t)bi * NTOT + gj] = q;
    }
}

// ---------- finalize: coalesced gather, masked mean of log1p(spos*sneg) ----------
__global__ __launch_bounds__(256) void finalize_kernel(const int* __restrict__ clab,
                                                       const int* __restrict__ meta,
                                                       const float* __restrict__ Ppos,
                                                       const float* __restrict__ Pneg,
                                                       float* __restrict__ accum) {
    int i = blockIdx.x * blockDim.x + threadIdx.x;
    const int npad = meta[1];
    const int nta = npad >> 7;
    float s = 0.0f, cnt = 0.0f;
    if (i < npad && clab[i] >= 0) {
        float sp = 0.0f, sn = 0.0f;
        for (int t = 0; t < nta; ++t) {
            sp += Ppos[(size_t)t * NTOT + i];
            sn += Pneg[(size_t)t * NTOT + i];
        }
        s = log1pf(sp * sn);
        cnt = 1.0f;
    }
    #pragma unroll
    for (int off = 1; off < 64; off <<= 1) {
        s   += __shfl_xor(s, off);
        cnt += __shfl_xor(cnt, off);
    }
    __shared__ float sh[8];
    int lane = threadIdx.x & 63, w = threadIdx.x >> 6;
    if (lane == 0) { sh[w] = s; sh[4 + w] = cnt; }
    __syncthreads();
    if (threadIdx.x == 0) {
        atomicAdd(&accum[0], sh[0] + sh[1] + sh[2] + sh[3]);
        atomicAdd(&accum[1], sh[4] + sh[5] + sh[6] + sh[7]);
    }
}

__global__ void writeout_kernel(const float* __restrict__ accum, float* __restrict__ out) {
    out[0] = accum[0] / accum[1];
}

extern "C" void kernel_launch(void* const* d_in, const int* in_sizes, int n_in,
                              void* d_out, int out_size, void* d_ws, size_t ws_size,
                              hipStream_t stream) {
    (void)in_sizes; (void)n_in; (void)out_size; (void)ws_size;
    const float* input_f = (const float*)d_in[0];
    const int*   target  = (const int*)d_in[1];
    float* out = (float*)d_out;

    char* ws = (char*)d_ws;
    const size_t FB_BYTES = (size_t)NTOT * DIM * 2;      // 14,155,776
    __hip_bfloat16* cfb = (__hip_bfloat16*)ws;
    char* p = ws + FB_BYTES;
    int*   clab  = (int*)p;            p += NTOT * 4;
    int*   offs  = (int*)p;            p += 4096;
    int*   meta  = (int*)p;            p += 256;
    float* accum = (float*)p;          p += 256;
    float* Ppos  = (float*)p;          p += (size_t)NTILES * NTOT * 4;  // 1.49 MB
    float* Pneg  = (float*)p;

    prepscan_kernel<<<dim3(1), dim3(256), 0, stream>>>(target, offs, meta, clab, accum);
    norm_c_kernel<<<dim3(NTOT / 4), dim3(256), 0, stream>>>(input_f, target, offs, cfb, clab);
    gemm_kernel<<<dim3(NTRI), dim3(256), 0, stream>>>(cfb, clab, meta, Ppos, Pneg);
    finalize_kernel<<<dim3((NTOT + 255) / 256), dim3(256), 0, stream>>>(clab, meta, Ppos, Pneg, accum);
    writeout_kernel<<<dim3(1), dim3(1), 0, stream>>>(accum, out);
}

// Round 6
// 77.239 us; speedup vs baseline: 1.1490x; 1.0866x over previous
//
#include <hip/hip_runtime.h>
#include <hip/hip_bf16.h>
#include <stdint.h>

#define BATCH 256
#define TSLOT 27
#define NTOT  (BATCH * TSLOT)   // 6912
#define DIM   1024
#define BM    128
#define NTILES 54               // NTOT / BM
#define NTRI  (NTILES * (NTILES + 1) / 2)  // 1485; active prefix ~ (npad/128)-triangle
#define KST   32                // DIM / 32

typedef __attribute__((ext_vector_type(8))) short short8;
typedef __attribute__((ext_vector_type(4))) float f32x4;

// ---------- prep + scan: offsets, meta, clab tail, accum zero ----------
__global__ __launch_bounds__(256) void prepscan_kernel(const int* __restrict__ tgt,
                                                       int* __restrict__ offs,
                                                       int* __restrict__ meta,
                                                       int* __restrict__ clab,
                                                       float* __restrict__ accum) {
    int b = threadIdx.x;
    const int* t = tgt + b * TSLOT;
    int fz = 1;
    for (int i = 1; i < TSLOT; ++i) {
        if (t[i] == 0) { fz = i; break; }
    }
    __shared__ int sh[256];
    sh[b] = fz;
    __syncthreads();
    for (int d = 1; d < 256; d <<= 1) {
        int v = (b >= d) ? sh[b - d] : 0;
        __syncthreads();
        sh[b] += v;
        __syncthreads();
    }
    offs[b] = sh[b] - fz;  // exclusive
    if (b < 2) accum[b] = 0.0f;
    __syncthreads();
    int nv = sh[255];
    int npad = ((nv + 127) / 128) * 128;
    if (b == 255) {
        offs[256] = nv;
        meta[0] = nv;
        meta[1] = npad;
    }
    if (b < npad - nv) clab[nv + b] = -1;
}

// ---------- wave-per-row L2-normalize f32 -> bf16, scatter compacted ----------
__global__ __launch_bounds__(256) void norm_c_kernel(const float* __restrict__ in,
                                                     const int* __restrict__ tgt,
                                                     const int* __restrict__ offs,
                                                     __hip_bfloat16* __restrict__ cfb,
                                                     int* __restrict__ clab) {
    const int wv   = blockIdx.x * 4 + (threadIdx.x >> 6);
    const int lane = threadIdx.x & 63;
    const int b = wv / TSLOT, t = wv - b * TSLOT;
    const int o0 = offs[b], o1 = offs[b + 1];
    if (t >= o1 - o0) return;
    const int dest = o0 + t;
    const float* src = in + (size_t)wv * DIM + lane * 16;
    float4 v0 = *(const float4*)(src);
    float4 v1 = *(const float4*)(src + 4);
    float4 v2 = *(const float4*)(src + 8);
    float4 v3 = *(const float4*)(src + 12);
    float ss = v0.x*v0.x + v0.y*v0.y + v0.z*v0.z + v0.w*v0.w
             + v1.x*v1.x + v1.y*v1.y + v1.z*v1.z + v1.w*v1.w
             + v2.x*v2.x + v2.y*v2.y + v2.z*v2.z + v2.w*v2.w
             + v3.x*v3.x + v3.y*v3.y + v3.z*v3.z + v3.w*v3.w;
    #pragma unroll
    for (int off = 1; off < 64; off <<= 1) ss += __shfl_xor(ss, off);
    const float scale = 1.0f / fmaxf(sqrtf(ss), 1e-12f);
    unsigned short h[16];
    float f[16] = {v0.x,v0.y,v0.z,v0.w, v1.x,v1.y,v1.z,v1.w,
                   v2.x,v2.y,v2.z,v2.w, v3.x,v3.y,v3.z,v3.w};
    #pragma unroll
    for (int j = 0; j < 16; ++j) {
        __hip_bfloat16 hv = __float2bfloat16(f[j] * scale);
        h[j] = *(unsigned short*)&hv;
    }
    unsigned short* dst = (unsigned short*)cfb + (size_t)dest * DIM + lane * 16;
    *(ushort4*)(dst)      = *(ushort4*)&h[0];
    *(ushort4*)(dst + 4)  = *(ushort4*)&h[4];
    *(ushort4*)(dst + 8)  = *(ushort4*)&h[8];
    *(ushort4*)(dst + 12) = *(ushort4*)&h[12];
    if (lane == 0) clab[dest] = tgt[wv];
}

// ---------- symmetric fused GEMM: 8 waves, 4-deep counted-vmcnt, BK=32 ----------
// 512 threads = 8 waves (2 row-strips x 4 col-strips); wave tile 64x32.
// 16 waves/CU (2 blocks) = 4 waves/SIMD -> 2x TLP vs the 4-wave R5 variant.
__global__ __launch_bounds__(512) void gemm_kernel(const __hip_bfloat16* __restrict__ fb,
                                                   const int* __restrict__ clab,
                                                   const int* __restrict__ meta,
                                                   float* __restrict__ Ppos,
                                                   float* __restrict__ Pneg) {
    __shared__ __align__(16) char lds[65536];  // 4 bufs x (A 8KB + B 8KB)

    int t = blockIdx.x;
    int bi = 0;
    while (t >= NTILES - bi) { t -= NTILES - bi; ++bi; }
    const int bj = bi + t;
    const int npad = meta[1];
    const int col0 = bj * BM;
    if (col0 >= npad) return;
    const int row0 = bi * BM;
    const bool diag = (bi == bj);

    const int tid  = threadIdx.x;
    const int lane = tid & 63;
    const int w    = tid >> 6;         // 0..7
    const int wm   = w & 1;            // row strip (64 rows)
    const int wn   = w >> 1;           // col strip (32 cols)

    f32x4 acc[4][2] = {};
    const char* fbyte = (const char*)fb;

    // stage: A/B panels 128 rows x 64 B = 8 KB = 512 chunks each; wave w: chunk w*64+lane
    auto stage = [&](int s) {
        char* buf = lds + (s & 3) * 16384;
        const int k0b = s * 64;
        const int c = w * 64 + lane;
        const int r = c >> 2, ks = c & 3;
        const int srcoff = ((ks ^ ((r >> 1) & 3)) << 4);
        const char* ga = fbyte + (size_t)(row0 + r) * (DIM * 2) + k0b + srcoff;
        __builtin_amdgcn_global_load_lds(
            (const __attribute__((address_space(1))) void*)ga,
            (__attribute__((address_space(3))) void*)(buf + c * 16),
            16, 0, 0);
        const char* gb = fbyte + (size_t)(col0 + r) * (DIM * 2) + k0b + srcoff;
        __builtin_amdgcn_global_load_lds(
            (const __attribute__((address_space(1))) void*)gb,
            (__attribute__((address_space(3))) void*)(buf + 8192 + c * 16),
            16, 0, 0);
    };

    const int rsel = lane & 15, tsl = lane >> 4;
    auto compute = [&](int s) {
        const char* bA = lds + (s & 3) * 16384;
        const char* bB = bA + 8192;
        short8 af[4], bf[2];
        #pragma unroll
        for (int m = 0; m < 4; ++m) {
            const int r = wm * 64 + m * 16 + rsel;
            af[m] = *(const short8*)(bA + r * 64 + ((tsl ^ ((r >> 1) & 3)) << 4));
        }
        #pragma unroll
        for (int n = 0; n < 2; ++n) {
            const int r = wn * 32 + n * 16 + rsel;
            bf[n] = *(const short8*)(bB + r * 64 + ((tsl ^ ((r >> 1) & 3)) << 4));
        }
        #pragma unroll
        for (int m = 0; m < 4; ++m)
            #pragma unroll
            for (int n = 0; n < 2; ++n)
                acc[m][n] = __builtin_amdgcn_mfma_f32_16x16x32_bf16(
                    af[m], bf[n], acc[m][n], 0, 0, 0);
    };

    stage(0); stage(1); stage(2);  // 6 loads/wave outstanding
    #pragma unroll 1
    for (int s = 0; s < KST - 3; ++s) {
        asm volatile("s_waitcnt vmcnt(4)" ::: "memory");   // own stage s landed
        __builtin_amdgcn_s_barrier();                      // all waves' stage s landed
        asm volatile("" ::: "memory");
        stage(s + 3);                                      // buf (s-1): all past compute(s-1)
        compute(s);
    }
    asm volatile("s_waitcnt vmcnt(4)" ::: "memory");
    __builtin_amdgcn_s_barrier();
    asm volatile("" ::: "memory");
    compute(KST - 3);
    asm volatile("s_waitcnt vmcnt(2)" ::: "memory");
    __builtin_amdgcn_s_barrier();
    asm volatile("" ::: "memory");
    compute(KST - 2);
    asm volatile("s_waitcnt vmcnt(0)" ::: "memory");
    __builtin_amdgcn_s_barrier();
    asm volatile("" ::: "memory");
    compute(KST - 1);

    // ---- epilogue: masked exp, cross-wave combine through LDS, coalesced stores ----
    // fl = buf0 (last read by compute(28); computes 29-31 read bufs 1-3) -> safe.
    const int c = rsel, g = tsl;
    float cpos[2] = {0, 0}, cneg[2] = {0, 0};
    float* fl = (float*)lds;

    #pragma unroll
    for (int m = 0; m < 4; ++m) {
        #pragma unroll
        for (int rg = 0; rg < 4; ++rg) {
            const int gi = row0 + wm * 64 + m * 16 + g * 4 + rg;
            const int li = clab[gi];
            float rp = 0.0f, rn = 0.0f;
            #pragma unroll
            for (int n = 0; n < 2; ++n) {
                const int gj = col0 + wn * 32 + n * 16 + c;
                const int lj = clab[gj];
                const float s = acc[m][n][rg];
                if (li >= 0 && lj >= 0) {
                    if (li == lj) { float e = __expf(-s); rp += e; cpos[n] += e; }
                    else          { float e = __expf(s);  rn += e; cneg[n] += e; }
                }
            }
            #pragma unroll
            for (int off = 1; off <= 8; off <<= 1) {
                rp += __shfl_xor(rp, off);
                rn += __shfl_xor(rn, off);
            }
            if (c == 0) {
                int lr = m * 16 + g * 4 + rg;          // 0..63
                fl[w * 64 + lr]        = rp;           // [0, 512)
                fl[512 + w * 64 + lr]  = rn;           // [512, 1024)
            }
        }
    }
    #pragma unroll
    for (int n = 0; n < 2; ++n) {
        float p = cpos[n], q = cneg[n];
        p += __shfl_xor(p, 16); p += __shfl_xor(p, 32);
        q += __shfl_xor(q, 16); q += __shfl_xor(q, 32);
        if (g == 0) {
            int lc = n * 16 + c;                       // 0..31
            fl[1024 + w * 32 + lc] = p;                // [1024, 1280)
            fl[1280 + w * 32 + lc] = q;                // [1280, 1536)
        }
    }
    __syncthreads();
    if (tid < 128) {
        // row credit: row strip sm = tid>>6; waves {sm, sm+2, sm+4, sm+6}
        int sm = tid >> 6, lr = tid & 63;
        float rp = 0.0f, rn = 0.0f;
        #pragma unroll
        for (int k = 0; k < 4; ++k) {
            rp += fl[(sm + 2 * k) * 64 + lr];
            rn += fl[512 + (sm + 2 * k) * 64 + lr];
        }
        int gi = row0 + tid;
        Ppos[(size_t)bj * NTOT + gi] = rp;   // slot bj (>= bi), coalesced
        Pneg[(size_t)bj * NTOT + gi] = rn;
    } else if (tid < 256 && !diag) {
        // col credit: col j; strip wn = j>>5; waves {wn*2, wn*2+1}
        int j = tid - 128, cn = j >> 5, lc = j & 31;
        float p = fl[1024 + (cn * 2) * 32 + lc] + fl[1024 + (cn * 2 + 1) * 32 + lc];
        float q = fl[1280 + (cn * 2) * 32 + lc] + fl[1280 + (cn * 2 + 1) * 32 + lc];
        int gj = col0 + j;
        Ppos[(size_t)bi * NTOT + gj] = p;    // slot bi (< bj), coalesced
        Pneg[(size_t)bi * NTOT + gj] = q;
    }
}

// ---------- finalize: coalesced gather, masked mean of log1p(spos*sneg) ----------
__global__ __launch_bounds__(256) void finalize_kernel(const int* __restrict__ clab,
                                                       const int* __restrict__ meta,
                                                       const float* __restrict__ Ppos,
                                                       const float* __restrict__ Pneg,
                                                       float* __restrict__ accum) {
    int i = blockIdx.x * blockDim.x + threadIdx.x;
    const int npad = meta[1];
    const int nta = npad >> 7;
    float s = 0.0f, cnt = 0.0f;
    if (i < npad && clab[i] >= 0) {
        float sp = 0.0f, sn = 0.0f;
        for (int t = 0; t < nta; ++t) {
            sp += Ppos[(size_t)t * NTOT + i];
            sn += Pneg[(size_t)t * NTOT + i];
        }
        s = log1pf(sp * sn);
        cnt = 1.0f;
    }
    #pragma unroll
    for (int off = 1; off < 64; off <<= 1) {
        s   += __shfl_xor(s, off);
        cnt += __shfl_xor(cnt, off);
    }
    __shared__ float sh[8];
    int lane = threadIdx.x & 63, w = threadIdx.x >> 6;
    if (lane == 0) { sh[w] = s; sh[4 + w] = cnt; }
    __syncthreads();
    if (threadIdx.x == 0) {
        atomicAdd(&accum[0], sh[0] + sh[1] + sh[2] + sh[3]);
        atomicAdd(&accum[1], sh[4] + sh[5] + sh[6] + sh[7]);
    }
}

__global__ void writeout_kernel(const float* __restrict__ accum, float* __restrict__ out) {
    out[0] = accum[0] / accum[1];
}

extern "C" void kernel_launch(void* const* d_in, const int* in_sizes, int n_in,
                              void* d_out, int out_size, void* d_ws, size_t ws_size,
                              hipStream_t stream) {
    (void)in_sizes; (void)n_in; (void)out_size; (void)ws_size;
    const float* input_f = (const float*)d_in[0];
    const int*   target  = (const int*)d_in[1];
    float* out = (float*)d_out;

    char* ws = (char*)d_ws;
    const size_t FB_BYTES = (size_t)NTOT * DIM * 2;      // 14,155,776
    __hip_bfloat16* cfb = (__hip_bfloat16*)ws;
    char* p = ws + FB_BYTES;
    int*   clab  = (int*)p;            p += NTOT * 4;
    int*   offs  = (int*)p;            p += 4096;
    int*   meta  = (int*)p;            p += 256;
    float* accum = (float*)p;          p += 256;
    float* Ppos  = (float*)p;          p += (size_t)NTILES * NTOT * 4;  // 1.49 MB
    float* Pneg  = (float*)p;

    prepscan_kernel<<<dim3(1), dim3(256), 0, stream>>>(target, offs, meta, clab, accum);
    norm_c_kernel<<<dim3(NTOT / 4), dim3(256), 0, stream>>>(input_f, target, offs, cfb, clab);
    gemm_kernel<<<dim3(NTRI), dim3(512), 0, stream>>>(cfb, clab, meta, Ppos, Pneg);
    finalize_kernel<<<dim3((NTOT + 255) / 256), dim3(256), 0, stream>>>(clab, meta, Ppos, Pneg, accum);
    writeout_kernel<<<dim3(1), dim3(1), 0, stream>>>(accum, out);
}